// Round 10
// baseline (327.542 us; speedup 1.0000x reference)
//
#include <hip/hip_runtime.h>
#include <hip/hip_bf16.h>

typedef unsigned short u16;
typedef __attribute__((ext_vector_type(8))) short bf16x8;
typedef __attribute__((ext_vector_type(4))) float f32x4;
typedef __attribute__((ext_vector_type(16))) float f32x16;
typedef __attribute__((ext_vector_type(4))) unsigned short u16x4;
typedef __attribute__((ext_vector_type(8))) unsigned short u16x8;

#define BATCH 4096
#define INF   1024
#define NH    4096   // 64 leaves * 64 hidden
#define OUTF  512
#define NLEAF 64
#define FDEPTH 6
#define ZSPL  4      // GEMM2 split-K ways

// Scratch as device globals (fully rewritten every call; no ws_size dependency).
__device__ __align__(16) u16  g_Xb[(size_t)BATCH * INF];     // x, bf16 (b,k)
__device__ __align__(16) u16  g_W1t[(size_t)NH * INF];       // W1 transposed: (n,k)
__device__ __align__(16) u16  g_W2t[(size_t)OUTF * NH];      // W2 transposed: (o,k)
__device__ __align__(16) u16  g_NWh[(size_t)64 * INF];       // node weights bf16 (row63=0)
__device__ __align__(16) u16  g_B2t[(size_t)OUTF * 64];      // b2s transposed (o,l) bf16
__device__ __align__(16) u16  g_Hb[(size_t)BATCH * NH];      // H' = mix*relu(h), bf16
__device__ __align__(16) float g_mix[(size_t)BATCH * NLEAF];
__device__ __align__(16) float g_part[(size_t)ZSPL * BATCH * OUTF];  // GEMM2 partials
__device__ int g_scnt[128];  // split-K semaphores, one per output tile (zeroed in prep)

__device__ inline u16 f2b(float f) {
  __hip_bfloat16 h = __float2bfloat16(f);
  return *reinterpret_cast<u16*>(&h);
}

// Direct global->LDS DMA, 16 B per lane; LDS dest = wave-uniform base + lane*16.
__device__ inline void async16(const u16* g, u16* l) {
  __builtin_amdgcn_global_load_lds((const __attribute__((address_space(1))) void*)g,
                                   (__attribute__((address_space(3))) void*)l, 16, 0, 0);
}

// ------------- merged prep: casts + transposes, section-decoded -------------
__global__ __launch_bounds__(256) void prep_kernel(
    const float* __restrict__ x, const float* __restrict__ nw,
    const float* __restrict__ w1s, const float* __restrict__ w2s,
    const float* __restrict__ b2s) {
  __shared__ float tile[64 * 65];
  const int b = blockIdx.x;
  const int t = threadIdx.x;

  if (b < 2048) {  // ---- cast x ----
    int i = (b * 256 + t) * 8;
    float4 v0 = *(const float4*)(x + i);
    float4 v1 = *(const float4*)(x + i + 4);
    u16x8 h;
    h[0] = f2b(v0.x); h[1] = f2b(v0.y); h[2] = f2b(v0.z); h[3] = f2b(v0.w);
    h[4] = f2b(v1.x); h[5] = f2b(v1.y); h[6] = f2b(v1.z); h[7] = f2b(v1.w);
    *(u16x8*)(g_Xb + i) = h;
    return;
  }
  if (b < 2112) {  // ---- cast nw ----
    int idx = ((b - 2048) * 256 + t) * 4;
    int n = idx >> 10;
    float4 v = make_float4(0.f, 0.f, 0.f, 0.f);
    if (n < 63) v = *(const float4*)(nw + idx);
    u16x4 h;
    h[0] = f2b(v.x); h[1] = f2b(v.y); h[2] = f2b(v.z); h[3] = f2b(v.w);
    *(u16x4*)(g_NWh + idx) = h;
    return;
  }

  // ---- transpose-cast sections: dst[c][r] = src[r][c] per 64x64 tile ----
  const float* sb;
  u16* db;
  int R, C, r0, c0;
  if (b < 3136) {
    int idx = b - 2112;
    int z = idx >> 4;
    R = 1024; C = 64;
    r0 = (idx & 15) * 64; c0 = 0;
    sb = w1s + (size_t)z * R * C;
    db = g_W1t + (size_t)z * R * C;
  } else if (b < 3648) {
    int idx = b - 3136;
    R = 4096; C = 512;
    r0 = (idx >> 3) * 64; c0 = (idx & 7) * 64;
    sb = w2s;
    db = g_W2t;
  } else {
    int idx = b - 3648;
    R = 64; C = 512;
    r0 = 0; c0 = idx * 64;
    sb = b2s;
    db = g_B2t;
    if (t < 16) g_scnt[idx * 16 + t] = 0;  // zero split-K semaphores every call
  }
  int cc4 = (t & 15) * 4;
#pragma unroll
  for (int it = 0; it < 4; ++it) {
    int rr = (t >> 4) + it * 16;
    float4 v = *(const float4*)(sb + (size_t)(r0 + rr) * C + c0 + cc4);
    tile[rr * 65 + cc4 + 0] = v.x;
    tile[rr * 65 + cc4 + 1] = v.y;
    tile[rr * 65 + cc4 + 2] = v.z;
    tile[rr * 65 + cc4 + 3] = v.w;
  }
  __syncthreads();
  int cc = t >> 2, rch = (t & 3) * 16;
  u16x8 o0, o1;
#pragma unroll
  for (int j = 0; j < 8; ++j) o0[j] = f2b(tile[(rch + j) * 65 + cc]);
#pragma unroll
  for (int j = 0; j < 8; ++j) o1[j] = f2b(tile[(rch + 8 + j) * 65 + cc]);
  u16* p = db + (size_t)(c0 + cc) * R + r0 + rch;
  *(u16x8*)p = o0;
  *(u16x8*)(p + 8) = o1;
}

// ------------- fused mixture: MFMA logits + sigmoid + tree product -> g_mix
//               + MFMA seed out = mix@b2 -------------
__global__ __launch_bounds__(256) void mixture_kernel(
    const float* __restrict__ nb, float* __restrict__ out) {
  __shared__ __align__(16) unsigned char lds[57344];
  const int t = threadIdx.x;
  const int wv = t >> 6, ln = t & 63;
  const int quad = ln >> 4, m16 = ln & 15;
  const int r0 = blockIdx.x * 16;

  u16* stW = (u16*)(lds + wv * 10240);
  u16* stX = (u16*)(lds + wv * 10240 + 8192);
  float* lred = (float*)lds;
  float* ssig = (float*)(lds + 16384);
  u16* smixb = (u16*)(lds + 20480);
  u16* b2l = (u16*)(lds + 24576);

  f32x4 acc[4] = {};
#pragma unroll 1
  for (int it = 0; it < 4; ++it) {
    int kc = wv * 256 + it * 64;
#pragma unroll
    for (int j = 0; j < 8; ++j) {
      int id = j * 64 + ln;
      int row = id >> 3, c8 = (id & 7) ^ (row & 7);
      async16(g_NWh + (size_t)row * INF + kc + c8 * 8, stW + j * 512);
    }
#pragma unroll
    for (int j = 0; j < 2; ++j) {
      int id = j * 64 + ln;
      int row = id >> 3, c8 = (id & 7) ^ (row & 7);
      async16(g_Xb + (size_t)(r0 + row) * INF + kc + c8 * 8, stX + j * 512);
    }
    __syncthreads();
#pragma unroll
    for (int ks = 0; ks < 2; ++ks) {
      bf16x8 bF = *(const bf16x8*)(stX + m16 * 64 + ((ks * 4 + quad) ^ (m16 & 7)) * 8);
#pragma unroll
      for (int tw = 0; tw < 4; ++tw) {
        int row = tw * 16 + m16;
        bf16x8 aF = *(const bf16x8*)(stW + row * 64 + ((ks * 4 + quad) ^ (row & 7)) * 8);
        acc[tw] = __builtin_amdgcn_mfma_f32_16x16x32_bf16(aF, bF, acc[tw], 0, 0, 0);
      }
    }
    __syncthreads();
  }
#pragma unroll
  for (int tw = 0; tw < 4; ++tw)
#pragma unroll
    for (int r = 0; r < 4; ++r)
      lred[((size_t)wv * 64 + tw * 16 + quad * 4 + r) * 16 + m16] = acc[tw][r];
  __syncthreads();

#pragma unroll
  for (int j = 0; j < 8; ++j) {
    int id = (wv * 8 + j) * 64 + ln;
    int row = id >> 3, c8 = (id & 7) ^ (row & 7);
    async16(g_B2t + (size_t)row * 64 + c8 * 8, b2l + (wv * 8 + j) * 512);
  }

  {
    int n = t & 63, rg = t >> 6;
#pragma unroll
    for (int rr = 0; rr < 4; ++rr) {
      int row = rg * 4 + rr;
      float s = lred[(0 * 64 + n) * 16 + row] + lred[(1 * 64 + n) * 16 + row] +
                lred[(2 * 64 + n) * 16 + row] + lred[(3 * 64 + n) * 16 + row];
      if (n < 63) s += nb[n];
      ssig[row * 64 + n] = 1.f / (1.f + __expf(-s));
    }
  }
  __syncthreads();
  {
    int leaf = t & 63, rg = t >> 6;
#pragma unroll
    for (int rr = 0; rr < 4; ++rr) {
      int row = rg * 4 + rr;
      float p = 1.f;
#pragma unroll
      for (int d = 0; d < FDEPTH; ++d) {
        int node = (1 << d) - 1 + (leaf >> (FDEPTH - d));
        int bit = (leaf >> (FDEPTH - 1 - d)) & 1;
        float s = ssig[row * 64 + node];
        p *= bit ? s : (1.f - s);
      }
      g_mix[(size_t)(r0 + row) * 64 + leaf] = p;
      smixb[row * 64 + ((leaf >> 3) ^ (row & 7)) * 8 + (leaf & 7)] = f2b(p);
    }
  }
  __syncthreads();

  bf16x8 mixF[2];
#pragma unroll
  for (int ks = 0; ks < 2; ++ks)
    mixF[ks] = *(const bf16x8*)(smixb + m16 * 64 + ((ks * 4 + quad) ^ (m16 & 7)) * 8);
#pragma unroll 1
  for (int s = 0; s < 2; ++s) {
    f32x4 sacc[4] = {};
#pragma unroll
    for (int tile = 0; tile < 4; ++tile) {
#pragma unroll
      for (int ks = 0; ks < 2; ++ks) {
        int lrow = wv * 64 + tile * 16 + m16;
        bf16x8 aF = *(const bf16x8*)(b2l + lrow * 64 + ((ks * 4 + quad) ^ (lrow & 7)) * 8);
        sacc[tile] = __builtin_amdgcn_mfma_f32_16x16x32_bf16(aF, mixF[ks], sacc[tile], 0, 0, 0);
      }
    }
#pragma unroll
    for (int tile = 0; tile < 4; ++tile) {
      int o = s * 256 + wv * 64 + tile * 16 + quad * 4;
      *(f32x4*)(out + (size_t)(r0 + m16) * OUTF + o) = sacc[tile];
    }
    if (s == 0) {
      __syncthreads();
#pragma unroll
      for (int j = 0; j < 8; ++j) {
        int id = (wv * 8 + j) * 64 + ln;
        int row = id >> 3, c8 = (id & 7) ^ (row & 7);
        async16(g_B2t + (size_t)(256 + row) * 64 + c8 * 8, b2l + (wv * 8 + j) * 512);
      }
      __syncthreads();
    }
  }
}

// ------------- GEMM1: H'(b,n) = mix * relu(Xb @ W1t^T + b1) -------------
// 32x32x16 MFMA + fragment-major LDS: slot j (16B chunks) holds
// (row = (j>>8)*32 + (j&31), kchunk = (j>>5)&7). Fragment reads are
// lane-linear (base + ks*1024B + lane*16B) -> conflict-free by construction
// (r9: XOR layout gave 4.19M conflict-cycles with the 32x32 read geometry).
__global__ __launch_bounds__(256) void gemm1_kernel(const float* __restrict__ b1) {
  constexpr int BM = 128, BN = 128, BK = 64, K = 1024, LD = 1024;

  __shared__ u16 lsA[BM * BK];  // batch rows (second operand)
  __shared__ u16 lsB[BN * BK];  // weight rows (first operand)

  const int t = threadIdx.x;
  const int wv = t >> 6, ln = t & 63;
  const int wm = wv >> 1, wn = wv & 1;
  const int l32 = ln & 31, lh = ln >> 5;
  const int am0 = blockIdx.y * BM;
  const int bn0 = blockIdx.x * BN;

  f32x16 acc[2][2] = {};  // [tw: col 32-tile][tb: batch 32-tile]

  for (int kc = 0; kc < K; kc += BK) {
#pragma unroll
    for (int i = 0; i < 4; ++i) {
      // slot j = i*256 + wv*64 + ln -> (row = i*32 + l32, c8 = wv*2 + lh)
      int row = i * 32 + l32;
      int c8 = wv * 2 + lh;
      const size_t goff = (size_t)row * LD + kc + c8 * 8;
      async16(g_Xb + (size_t)am0 * LD + goff, lsA + (i * 256 + wv * 64) * 8);
      async16(g_W1t + (size_t)bn0 * LD + goff, lsB + (i * 256 + wv * 64) * 8);
    }
    __syncthreads();
#pragma unroll
    for (int ks = 0; ks < 4; ++ks) {  // K=16 per step
      bf16x8 wF[2], xF[2];
#pragma unroll
      for (int tw = 0; tw < 2; ++tw)
        wF[tw] = *(const bf16x8*)(lsB + (wn * 2 + tw) * 2048 + ks * 512 + ln * 8);
#pragma unroll
      for (int tb = 0; tb < 2; ++tb)
        xF[tb] = *(const bf16x8*)(lsA + (wm * 2 + tb) * 2048 + ks * 512 + ln * 8);
#pragma unroll
      for (int tw = 0; tw < 2; ++tw)
#pragma unroll
        for (int tb = 0; tb < 2; ++tb)
          acc[tw][tb] = __builtin_amdgcn_mfma_f32_32x32x16_bf16(wF[tw], xF[tb], acc[tw][tb], 0, 0, 0);
    }
    __syncthreads();
  }

  const int leaf = (bn0 >> 6) + wn;
#pragma unroll
  for (int tb = 0; tb < 2; ++tb) {
    int bg = am0 + wm * 64 + tb * 32 + l32;
    float mixv = g_mix[(size_t)bg * 64 + leaf];
#pragma unroll
    for (int tw = 0; tw < 2; ++tw) {
#pragma unroll
      for (int g = 0; g < 4; ++g) {
        int col0 = bn0 + wn * 64 + tw * 32 + g * 8 + lh * 4;
        float4 b1v = *(const float4*)(b1 + col0);
        u16x4 pk;
        pk[0] = f2b(fmaxf(acc[tw][tb][g * 4 + 0] + b1v.x, 0.f) * mixv);
        pk[1] = f2b(fmaxf(acc[tw][tb][g * 4 + 1] + b1v.y, 0.f) * mixv);
        pk[2] = f2b(fmaxf(acc[tw][tb][g * 4 + 2] + b1v.z, 0.f) * mixv);
        pk[3] = f2b(fmaxf(acc[tw][tb][g * 4 + 3] + b1v.w, 0.f) * mixv);
        *(u16x4*)(g_Hb + (size_t)bg * NH + col0) = pk;
      }
    }
  }
}

// ------------- GEMM2: out += Hb @ W2t^T, split-K with fused last-arriver
//               reduction (semaphore per output tile) -------------
// Flat 512-block grid, XCD-swizzled (r8: cut FETCH 107->~64 MB).
__global__ __launch_bounds__(256) void gemm2_kernel(float* __restrict__ out) {
  constexpr int BM = 128, BN = 128, BK = 64, K = 4096, LD = 4096;

  __shared__ u16 lsA[BM * BK];
  __shared__ u16 lsB[BN * BK];

  const int bid = blockIdx.x;
  const int xcd = bid & 7, slot = bid >> 3;        // 64 slots per XCD
  const int ytile = xcd * 4 + (slot >> 4);
  const int rem = slot & 15;
  const int xtile = rem & 3, zidx = rem >> 2;

  const int t = threadIdx.x;
  const int wv = t >> 6, ln = t & 63;
  const int wm = wv >> 1, wn = wv & 1;
  const int quad = ln >> 4, m16 = ln & 15;
  const int am0 = ytile * BM;
  const int bn0 = xtile * BN;
  const int kbeg = zidx * (K / ZSPL);
  const int kend = kbeg + K / ZSPL;

  f32x4 acc[4][4] = {};

  for (int kc = kbeg; kc < kend; kc += BK) {
#pragma unroll
    for (int i = 0; i < 4; ++i) {
      int id = i * 256 + t;
      int row = id >> 3;
      int c8 = (id & 7) ^ (row & 7);
      async16(g_Hb + (size_t)(am0 + row) * LD + kc + c8 * 8, lsA + (i * 256 + wv * 64) * 8);
    }
#pragma unroll
    for (int i = 0; i < 4; ++i) {
      int id = i * 256 + t;
      int row = id >> 3;
      int c8 = (id & 7) ^ (row & 7);
      async16(g_W2t + (size_t)(bn0 + row) * LD + kc + c8 * 8, lsB + (i * 256 + wv * 64) * 8);
    }
    __syncthreads();
#pragma unroll
    for (int ks = 0; ks < 2; ++ks) {
      bf16x8 wF[4], xF[4];
#pragma unroll
      for (int tw = 0; tw < 4; ++tw) {
        int row = wn * 64 + tw * 16 + m16;
        wF[tw] = *(const bf16x8*)(lsB + row * BK + ((ks * 4 + quad) ^ (row & 7)) * 8);
      }
#pragma unroll
      for (int tb = 0; tb < 4; ++tb) {
        int row = wm * 64 + tb * 16 + m16;
        xF[tb] = *(const bf16x8*)(lsA + row * BK + ((ks * 4 + quad) ^ (row & 7)) * 8);
      }
#pragma unroll
      for (int tw = 0; tw < 4; ++tw)
#pragma unroll
        for (int tb = 0; tb < 4; ++tb)
          acc[tw][tb] = __builtin_amdgcn_mfma_f32_16x16x32_bf16(wF[tw], xF[tb], acc[tw][tb], 0, 0, 0);
    }
    __syncthreads();
  }

  {
    float* part = g_part + (size_t)zidx * ((size_t)BATCH * OUTF);
#pragma unroll
    for (int tw = 0; tw < 4; ++tw) {
      int og = bn0 + wn * 64 + tw * 16 + quad * 4;
#pragma unroll
      for (int tb = 0; tb < 4; ++tb) {
        int bg = am0 + wm * 64 + tb * 16 + m16;
        *(f32x4*)(part + (size_t)bg * OUTF + og) = acc[tw][tb];
      }
    }
  }

  // last-arriver reduction: release partials, bump semaphore; 4th block sums.
  __threadfence();
  __shared__ int swin;
  if (t == 0) {
    int old = atomicAdd(&g_scnt[ytile * 4 + xtile], 1);
    swin = (old == ZSPL - 1) ? 1 : 0;
  }
  __syncthreads();
  if (swin) {
    __threadfence();  // acquire: peers' partial stores now visible
    const size_t base = (size_t)am0 * OUTF + bn0;
#pragma unroll
    for (int c = 0; c < 16; ++c) {
      int idx = (c * 256 + t) * 4;        // f32 index within the 128x128 tile
      int row = idx >> 7, col = idx & 127;
      size_t off = base + (size_t)row * OUTF + col;
      float4 s = *(const float4*)(out + off);  // seed = mix @ b2s
#pragma unroll
      for (int z = 0; z < ZSPL; ++z) {
        const float4 p = *(const float4*)(g_part + (size_t)z * BATCH * OUTF + off);
        s.x += p.x; s.y += p.y; s.z += p.z; s.w += p.w;
      }
      *(float4*)(out + off) = s;
    }
  }
}

extern "C" void kernel_launch(void* const* d_in, const int* in_sizes, int n_in,
                              void* d_out, int out_size, void* d_ws, size_t ws_size,
                              hipStream_t stream) {
  const float* x = (const float*)d_in[0];
  const float* nw = (const float*)d_in[1];
  const float* nb = (const float*)d_in[2];
  const float* w1s = (const float*)d_in[3];
  const float* b1s = (const float*)d_in[4];
  const float* w2s = (const float*)d_in[5];
  const float* b2s = (const float*)d_in[6];
  float* out = (float*)d_out;
  (void)d_ws; (void)ws_size;

  hipLaunchKernelGGL(prep_kernel, dim3(3656), dim3(256), 0, stream,
                     x, nw, w1s, w2s, b2s);
  hipLaunchKernelGGL(mixture_kernel, dim3(256), dim3(256), 0, stream, nb, out);
  hipLaunchKernelGGL(gemm1_kernel, dim3(32, 32), dim3(256), 0, stream, b1s);
  hipLaunchKernelGGL(gemm2_kernel, dim3(512), dim3(256), 0, stream, out);
}

// Round 11
// 204.783 us; speedup vs baseline: 1.5995x; 1.5995x over previous
//
#include <hip/hip_runtime.h>
#include <hip/hip_bf16.h>

typedef unsigned short u16;
typedef __attribute__((ext_vector_type(8))) short bf16x8;
typedef __attribute__((ext_vector_type(4))) float f32x4;
typedef __attribute__((ext_vector_type(4))) unsigned short u16x4;
typedef __attribute__((ext_vector_type(8))) unsigned short u16x8;

#define BATCH 4096
#define INF   1024
#define NH    4096   // 64 leaves * 64 hidden
#define OUTF  512
#define NLEAF 64
#define FDEPTH 6
#define ZSPL  4      // GEMM2 split-K ways

// Scratch as device globals (fully rewritten every call; no ws_size dependency).
__device__ __align__(16) u16  g_Xb[(size_t)BATCH * INF];     // x, bf16 (b,k)
__device__ __align__(16) u16  g_W1t[(size_t)NH * INF];       // W1 transposed: (n,k)
__device__ __align__(16) u16  g_W2t[(size_t)OUTF * NH];      // W2 transposed: (o,k)
__device__ __align__(16) u16  g_NWh[(size_t)64 * INF];       // node weights bf16 (row63=0)
__device__ __align__(16) u16  g_B2t[(size_t)OUTF * 64];      // b2s transposed (o,l) bf16
__device__ __align__(16) u16  g_Hb[(size_t)BATCH * NH];      // H' = mix*relu(h), bf16
__device__ __align__(16) float g_mix[(size_t)BATCH * NLEAF];
__device__ __align__(16) float g_part[(size_t)ZSPL * BATCH * OUTF];  // GEMM2 partials

__device__ inline u16 f2b(float f) {
  __hip_bfloat16 h = __float2bfloat16(f);
  return *reinterpret_cast<u16*>(&h);
}

// Direct global->LDS DMA, 16 B per lane; LDS dest = wave-uniform base + lane*16.
__device__ inline void async16(const u16* g, u16* l) {
  __builtin_amdgcn_global_load_lds((const __attribute__((address_space(1))) void*)g,
                                   (__attribute__((address_space(3))) void*)l, 16, 0, 0);
}

// ------------- merged prep: casts + transposes, section-decoded -------------
__global__ __launch_bounds__(256) void prep_kernel(
    const float* __restrict__ x, const float* __restrict__ nw,
    const float* __restrict__ w1s, const float* __restrict__ w2s,
    const float* __restrict__ b2s) {
  __shared__ float tile[64 * 65];
  const int b = blockIdx.x;
  const int t = threadIdx.x;

  if (b < 2048) {  // ---- cast x ----
    int i = (b * 256 + t) * 8;
    float4 v0 = *(const float4*)(x + i);
    float4 v1 = *(const float4*)(x + i + 4);
    u16x8 h;
    h[0] = f2b(v0.x); h[1] = f2b(v0.y); h[2] = f2b(v0.z); h[3] = f2b(v0.w);
    h[4] = f2b(v1.x); h[5] = f2b(v1.y); h[6] = f2b(v1.z); h[7] = f2b(v1.w);
    *(u16x8*)(g_Xb + i) = h;
    return;
  }
  if (b < 2112) {  // ---- cast nw ----
    int idx = ((b - 2048) * 256 + t) * 4;
    int n = idx >> 10;
    float4 v = make_float4(0.f, 0.f, 0.f, 0.f);
    if (n < 63) v = *(const float4*)(nw + idx);
    u16x4 h;
    h[0] = f2b(v.x); h[1] = f2b(v.y); h[2] = f2b(v.z); h[3] = f2b(v.w);
    *(u16x4*)(g_NWh + idx) = h;
    return;
  }

  // ---- transpose-cast sections: dst[c][r] = src[r][c] per 64x64 tile ----
  const float* sb;
  u16* db;
  int R, C, r0, c0;
  if (b < 3136) {
    int idx = b - 2112;
    int z = idx >> 4;
    R = 1024; C = 64;
    r0 = (idx & 15) * 64; c0 = 0;
    sb = w1s + (size_t)z * R * C;
    db = g_W1t + (size_t)z * R * C;
  } else if (b < 3648) {
    int idx = b - 3136;
    R = 4096; C = 512;
    r0 = (idx >> 3) * 64; c0 = (idx & 7) * 64;
    sb = w2s;
    db = g_W2t;
  } else {
    int idx = b - 3648;
    R = 64; C = 512;
    r0 = 0; c0 = idx * 64;
    sb = b2s;
    db = g_B2t;
  }
  int cc4 = (t & 15) * 4;
#pragma unroll
  for (int it = 0; it < 4; ++it) {
    int rr = (t >> 4) + it * 16;
    float4 v = *(const float4*)(sb + (size_t)(r0 + rr) * C + c0 + cc4);
    tile[rr * 65 + cc4 + 0] = v.x;
    tile[rr * 65 + cc4 + 1] = v.y;
    tile[rr * 65 + cc4 + 2] = v.z;
    tile[rr * 65 + cc4 + 3] = v.w;
  }
  __syncthreads();
  int cc = t >> 2, rch = (t & 3) * 16;
  u16x8 o0, o1;
#pragma unroll
  for (int j = 0; j < 8; ++j) o0[j] = f2b(tile[(rch + j) * 65 + cc]);
#pragma unroll
  for (int j = 0; j < 8; ++j) o1[j] = f2b(tile[(rch + 8 + j) * 65 + cc]);
  u16* p = db + (size_t)(c0 + cc) * R + r0 + rch;
  *(u16x8*)p = o0;
  *(u16x8*)(p + 8) = o1;
}

// ------------- fused mixture: MFMA logits + sigmoid + tree product -> g_mix
//               + MFMA seed out = mix@b2 -------------
__global__ __launch_bounds__(256) void mixture_kernel(
    const float* __restrict__ nb, float* __restrict__ out) {
  __shared__ __align__(16) unsigned char lds[57344];
  const int t = threadIdx.x;
  const int wv = t >> 6, ln = t & 63;
  const int quad = ln >> 4, m16 = ln & 15;
  const int r0 = blockIdx.x * 16;

  u16* stW = (u16*)(lds + wv * 10240);
  u16* stX = (u16*)(lds + wv * 10240 + 8192);
  float* lred = (float*)lds;
  float* ssig = (float*)(lds + 16384);
  u16* smixb = (u16*)(lds + 20480);
  u16* b2l = (u16*)(lds + 24576);

  f32x4 acc[4] = {};
#pragma unroll 1
  for (int it = 0; it < 4; ++it) {
    int kc = wv * 256 + it * 64;
#pragma unroll
    for (int j = 0; j < 8; ++j) {
      int id = j * 64 + ln;
      int row = id >> 3, c8 = (id & 7) ^ (row & 7);
      async16(g_NWh + (size_t)row * INF + kc + c8 * 8, stW + j * 512);
    }
#pragma unroll
    for (int j = 0; j < 2; ++j) {
      int id = j * 64 + ln;
      int row = id >> 3, c8 = (id & 7) ^ (row & 7);
      async16(g_Xb + (size_t)(r0 + row) * INF + kc + c8 * 8, stX + j * 512);
    }
    __syncthreads();
#pragma unroll
    for (int ks = 0; ks < 2; ++ks) {
      bf16x8 bF = *(const bf16x8*)(stX + m16 * 64 + ((ks * 4 + quad) ^ (m16 & 7)) * 8);
#pragma unroll
      for (int tw = 0; tw < 4; ++tw) {
        int row = tw * 16 + m16;
        bf16x8 aF = *(const bf16x8*)(stW + row * 64 + ((ks * 4 + quad) ^ (row & 7)) * 8);
        acc[tw] = __builtin_amdgcn_mfma_f32_16x16x32_bf16(aF, bF, acc[tw], 0, 0, 0);
      }
    }
    __syncthreads();
  }
#pragma unroll
  for (int tw = 0; tw < 4; ++tw)
#pragma unroll
    for (int r = 0; r < 4; ++r)
      lred[((size_t)wv * 64 + tw * 16 + quad * 4 + r) * 16 + m16] = acc[tw][r];
  __syncthreads();

#pragma unroll
  for (int j = 0; j < 8; ++j) {
    int id = (wv * 8 + j) * 64 + ln;
    int row = id >> 3, c8 = (id & 7) ^ (row & 7);
    async16(g_B2t + (size_t)row * 64 + c8 * 8, b2l + (wv * 8 + j) * 512);
  }

  {
    int n = t & 63, rg = t >> 6;
#pragma unroll
    for (int rr = 0; rr < 4; ++rr) {
      int row = rg * 4 + rr;
      float s = lred[(0 * 64 + n) * 16 + row] + lred[(1 * 64 + n) * 16 + row] +
                lred[(2 * 64 + n) * 16 + row] + lred[(3 * 64 + n) * 16 + row];
      if (n < 63) s += nb[n];
      ssig[row * 64 + n] = 1.f / (1.f + __expf(-s));
    }
  }
  __syncthreads();
  {
    int leaf = t & 63, rg = t >> 6;
#pragma unroll
    for (int rr = 0; rr < 4; ++rr) {
      int row = rg * 4 + rr;
      float p = 1.f;
#pragma unroll
      for (int d = 0; d < FDEPTH; ++d) {
        int node = (1 << d) - 1 + (leaf >> (FDEPTH - d));
        int bit = (leaf >> (FDEPTH - 1 - d)) & 1;
        float s = ssig[row * 64 + node];
        p *= bit ? s : (1.f - s);
      }
      g_mix[(size_t)(r0 + row) * 64 + leaf] = p;
      smixb[row * 64 + ((leaf >> 3) ^ (row & 7)) * 8 + (leaf & 7)] = f2b(p);
    }
  }
  __syncthreads();

  bf16x8 mixF[2];
#pragma unroll
  for (int ks = 0; ks < 2; ++ks)
    mixF[ks] = *(const bf16x8*)(smixb + m16 * 64 + ((ks * 4 + quad) ^ (m16 & 7)) * 8);
#pragma unroll 1
  for (int s = 0; s < 2; ++s) {
    f32x4 sacc[4] = {};
#pragma unroll
    for (int tile = 0; tile < 4; ++tile) {
#pragma unroll
      for (int ks = 0; ks < 2; ++ks) {
        int lrow = wv * 64 + tile * 16 + m16;
        bf16x8 aF = *(const bf16x8*)(b2l + lrow * 64 + ((ks * 4 + quad) ^ (lrow & 7)) * 8);
        sacc[tile] = __builtin_amdgcn_mfma_f32_16x16x32_bf16(aF, mixF[ks], sacc[tile], 0, 0, 0);
      }
    }
#pragma unroll
    for (int tile = 0; tile < 4; ++tile) {
      int o = s * 256 + wv * 64 + tile * 16 + quad * 4;
      *(f32x4*)(out + (size_t)(r0 + m16) * OUTF + o) = sacc[tile];
    }
    if (s == 0) {
      __syncthreads();
#pragma unroll
      for (int j = 0; j < 8; ++j) {
        int id = (wv * 8 + j) * 64 + ln;
        int row = id >> 3, c8 = (id & 7) ^ (row & 7);
        async16(g_B2t + (size_t)(256 + row) * 64 + c8 * 8, b2l + (wv * 8 + j) * 512);
      }
      __syncthreads();
    }
  }
}

// ------------- GEMM1: H'(b,n) = mix * relu(Xb @ W1t^T + b1) -------------
// 16x16x32 MFMA, XOR-swizzled LDS (measured 0 bank conflicts; the 32x32 read
// geometry costs a structural +4 cyc/ds_read_b128 [r9], and fragment-major
// staging throttles the DMA coalescing [r10] -- both reverted).
__global__ __launch_bounds__(256) void gemm1_kernel(const float* __restrict__ b1) {
  constexpr int BM = 128, BN = 128, BK = 64, K = 1024, LD = 1024;

  __shared__ u16 lsA[BM * BK];  // batch rows (second operand)
  __shared__ u16 lsB[BN * BK];  // weight rows (first operand)

  const int t = threadIdx.x;
  const int wv = t >> 6, ln = t & 63;
  const int wm = wv >> 1, wn = wv & 1;
  const int quad = ln >> 4, m16 = ln & 15;
  const int am0 = blockIdx.y * BM;
  const int bn0 = blockIdx.x * BN;

  f32x4 acc[4][4] = {};  // [tw: col tile][tb: batch tile]

  for (int kc = 0; kc < K; kc += BK) {
#pragma unroll
    for (int i = 0; i < 4; ++i) {
      int id = i * 256 + t;
      int row = id >> 3;
      int c8 = (id & 7) ^ (row & 7);
      async16(g_Xb + (size_t)(am0 + row) * LD + kc + c8 * 8, lsA + (i * 256 + wv * 64) * 8);
    }
#pragma unroll
    for (int i = 0; i < 4; ++i) {
      int id = i * 256 + t;
      int row = id >> 3;
      int c8 = (id & 7) ^ (row & 7);
      async16(g_W1t + (size_t)(bn0 + row) * LD + kc + c8 * 8, lsB + (i * 256 + wv * 64) * 8);
    }
    __syncthreads();
#pragma unroll
    for (int ks = 0; ks < 2; ++ks) {
      bf16x8 wF[4], xF[4];
#pragma unroll
      for (int tw = 0; tw < 4; ++tw) {
        int row = wn * 64 + tw * 16 + m16;
        wF[tw] = *(const bf16x8*)(lsB + row * BK + ((ks * 4 + quad) ^ (row & 7)) * 8);
      }
#pragma unroll
      for (int tb = 0; tb < 4; ++tb) {
        int row = wm * 64 + tb * 16 + m16;
        xF[tb] = *(const bf16x8*)(lsA + row * BK + ((ks * 4 + quad) ^ (row & 7)) * 8);
      }
#pragma unroll
      for (int tw = 0; tw < 4; ++tw)
#pragma unroll
        for (int tb = 0; tb < 4; ++tb)
          acc[tw][tb] = __builtin_amdgcn_mfma_f32_16x16x32_bf16(wF[tw], xF[tb], acc[tw][tb], 0, 0, 0);
    }
    __syncthreads();
  }

  const int leaf = (bn0 >> 6) + wn;
  float mix4[4];
#pragma unroll
  for (int tb = 0; tb < 4; ++tb) {
    int bg = am0 + wm * 64 + tb * 16 + m16;
    mix4[tb] = g_mix[(size_t)bg * 64 + leaf];
  }
#pragma unroll
  for (int tw = 0; tw < 4; ++tw) {
    int n0g = bn0 + wn * 64 + tw * 16 + quad * 4;
    float4 b1v = *(const float4*)(b1 + n0g);
#pragma unroll
    for (int tb = 0; tb < 4; ++tb) {
      int bg = am0 + wm * 64 + tb * 16 + m16;
      f32x4 a = acc[tw][tb];
      u16x4 pk;
      pk[0] = f2b(fmaxf(a[0] + b1v.x, 0.f) * mix4[tb]);
      pk[1] = f2b(fmaxf(a[1] + b1v.y, 0.f) * mix4[tb]);
      pk[2] = f2b(fmaxf(a[2] + b1v.z, 0.f) * mix4[tb]);
      pk[3] = f2b(fmaxf(a[3] + b1v.w, 0.f) * mix4[tb]);
      *(u16x4*)(g_Hb + (size_t)bg * NH + n0g) = pk;
    }
  }
}

// ------------- GEMM2: part[z](b,o) = Hb @ W2t^T (split-K partials) -------------
// Flat 512-block grid, XCD-swizzled (r8: cut FETCH 107->~55 MB). No fused
// reduction: device-scope fences forced per-block L2 flushes (r10: 152 us).
__global__ __launch_bounds__(256) void gemm2_kernel() {
  constexpr int BM = 128, BN = 128, BK = 64, K = 4096, LD = 4096;

  __shared__ u16 lsA[BM * BK];
  __shared__ u16 lsB[BN * BK];

  const int bid = blockIdx.x;
  const int xcd = bid & 7, slot = bid >> 3;        // 64 slots per XCD
  const int ytile = xcd * 4 + (slot >> 4);
  const int rem = slot & 15;
  const int xtile = rem & 3, zidx = rem >> 2;

  const int t = threadIdx.x;
  const int wv = t >> 6, ln = t & 63;
  const int wm = wv >> 1, wn = wv & 1;
  const int quad = ln >> 4, m16 = ln & 15;
  const int am0 = ytile * BM;
  const int bn0 = xtile * BN;
  const int kbeg = zidx * (K / ZSPL);
  const int kend = kbeg + K / ZSPL;

  f32x4 acc[4][4] = {};

  for (int kc = kbeg; kc < kend; kc += BK) {
#pragma unroll
    for (int i = 0; i < 4; ++i) {
      int id = i * 256 + t;
      int row = id >> 3;
      int c8 = (id & 7) ^ (row & 7);
      async16(g_Hb + (size_t)(am0 + row) * LD + kc + c8 * 8, lsA + (i * 256 + wv * 64) * 8);
    }
#pragma unroll
    for (int i = 0; i < 4; ++i) {
      int id = i * 256 + t;
      int row = id >> 3;
      int c8 = (id & 7) ^ (row & 7);
      async16(g_W2t + (size_t)(bn0 + row) * LD + kc + c8 * 8, lsB + (i * 256 + wv * 64) * 8);
    }
    __syncthreads();
#pragma unroll
    for (int ks = 0; ks < 2; ++ks) {
      bf16x8 wF[4], xF[4];
#pragma unroll
      for (int tw = 0; tw < 4; ++tw) {
        int row = wn * 64 + tw * 16 + m16;
        wF[tw] = *(const bf16x8*)(lsB + row * BK + ((ks * 4 + quad) ^ (row & 7)) * 8);
      }
#pragma unroll
      for (int tb = 0; tb < 4; ++tb) {
        int row = wm * 64 + tb * 16 + m16;
        xF[tb] = *(const bf16x8*)(lsA + row * BK + ((ks * 4 + quad) ^ (row & 7)) * 8);
      }
#pragma unroll
      for (int tw = 0; tw < 4; ++tw)
#pragma unroll
        for (int tb = 0; tb < 4; ++tb)
          acc[tw][tb] = __builtin_amdgcn_mfma_f32_16x16x32_bf16(wF[tw], xF[tb], acc[tw][tb], 0, 0, 0);
    }
    __syncthreads();
  }

  float* part = g_part + (size_t)zidx * ((size_t)BATCH * OUTF);
#pragma unroll
  for (int tw = 0; tw < 4; ++tw) {
    int og = bn0 + wn * 64 + tw * 16 + quad * 4;
#pragma unroll
    for (int tb = 0; tb < 4; ++tb) {
      int bg = am0 + wm * 64 + tb * 16 + m16;
      *(f32x4*)(part + (size_t)bg * OUTF + og) = acc[tw][tb];
    }
  }
}

// ------------- out += sum_z part[z] -------------
__global__ __launch_bounds__(256) void reduce_kernel(float* __restrict__ out) {
  int i = (blockIdx.x * 256 + threadIdx.x) * 4;
  float4 s = *(const float4*)(out + i);  // seed = mix @ b2s
#pragma unroll
  for (int z = 0; z < ZSPL; ++z) {
    const float4 p = *(const float4*)(g_part + (size_t)z * BATCH * OUTF + i);
    s.x += p.x; s.y += p.y; s.z += p.z; s.w += p.w;
  }
  *(float4*)(out + i) = s;
}

extern "C" void kernel_launch(void* const* d_in, const int* in_sizes, int n_in,
                              void* d_out, int out_size, void* d_ws, size_t ws_size,
                              hipStream_t stream) {
  const float* x = (const float*)d_in[0];
  const float* nw = (const float*)d_in[1];
  const float* nb = (const float*)d_in[2];
  const float* w1s = (const float*)d_in[3];
  const float* b1s = (const float*)d_in[4];
  const float* w2s = (const float*)d_in[5];
  const float* b2s = (const float*)d_in[6];
  float* out = (float*)d_out;
  (void)d_ws; (void)ws_size;

  hipLaunchKernelGGL(prep_kernel, dim3(3656), dim3(256), 0, stream,
                     x, nw, w1s, w2s, b2s);
  hipLaunchKernelGGL(mixture_kernel, dim3(256), dim3(256), 0, stream, nb, out);
  hipLaunchKernelGGL(gemm1_kernel, dim3(32, 32), dim3(256), 0, stream, b1s);
  hipLaunchKernelGGL(gemm2_kernel, dim3(512), dim3(256), 0, stream);
  hipLaunchKernelGGL(reduce_kernel, dim3(2048), dim3(256), 0, stream, out);
}